// Round 10
// baseline (281.770 us; speedup 1.0000x reference)
//
#include <hip/hip_runtime.h>
#include <stdint.h>

#define S_LEN 2048
#define HIDDEN 1024
#define NH 16
#define NKV 4
#define HD 64

typedef unsigned short u16;
typedef __attribute__((ext_vector_type(8))) short short8;
typedef __attribute__((ext_vector_type(4))) float f32x4;
typedef __attribute__((ext_vector_type(16))) float f32x16;
typedef __attribute__((ext_vector_type(4))) uint32_t u32x4;

__device__ __forceinline__ u16 f2b(float f) {
  uint32_t u = __float_as_uint(f);
  uint32_t r = u + 0x7fffu + ((u >> 16) & 1u);
  return (u16)(r >> 16);
}
__device__ __forceinline__ float b2f(u16 b) {
  return __uint_as_float(((uint32_t)b) << 16);
}
__device__ __forceinline__ void gll16(const void* g, void* l) {
  __builtin_amdgcn_global_load_lds(
      (const __attribute__((address_space(1))) uint32_t*)g,
      (__attribute__((address_space(3))) uint32_t*)l, 16, 0, 0);
}

// ---------------- fp32 -> bf16 convert, 5 buffers fused, 8 elem/thread ------
__global__ __launch_bounds__(256) void f2b_multi(
    const float* __restrict__ s0, u16* __restrict__ d0, int n0,
    const float* __restrict__ s1, u16* __restrict__ d1, int n1,
    const float* __restrict__ s2, u16* __restrict__ d2, int n2,
    const float* __restrict__ s3, u16* __restrict__ d3, int n3,
    const float* __restrict__ s4, u16* __restrict__ d4, int n4) {
  int i = blockIdx.x * 256 + threadIdx.x;
  const float* s;
  u16* d;
  int idx = i;
  if (i < n0) { s = s0; d = d0; }
  else if ((idx = i - n0) < n1) { s = s1; d = d1; }
  else if ((idx = i - n0 - n1) < n2) { s = s2; d = d2; }
  else if ((idx = i - n0 - n1 - n2) < n3) { s = s3; d = d3; }
  else if ((idx = i - n0 - n1 - n2 - n3) < n4) { s = s4; d = d4; }
  else return;
  f32x4 a = *reinterpret_cast<const f32x4*>(&s[(size_t)idx * 8]);
  f32x4 b = *reinterpret_cast<const f32x4*>(&s[(size_t)idx * 8 + 4]);
  short8 t;
#pragma unroll
  for (int k = 0; k < 4; ++k) t[k] = (short)f2b(a[k]);
#pragma unroll
  for (int k = 0; k < 4; ++k) t[4 + k] = (short)f2b(b[k]);
  *reinterpret_cast<short8*>(&d[(size_t)idx * 8]) = t;
}

// ---------------- bf16 GEMM: C = A * B^T (A:[M][K], B:[N][K]) ----------------
// 128x128 tile, BK=64, 8 waves (2M x 4N, each wave 64x32), mfma 16x16x32.
template <int OUT_BF16>
__global__ __launch_bounds__(512) void gemm_bt(const u16* __restrict__ A,
                                               const u16* __restrict__ B,
                                               void* __restrict__ Cv,
                                               int M, int N, int K) {
  __shared__ u16 As[128][64];
  __shared__ u16 Bs[128][64];
  const int tid = threadIdx.x;
  const int wid = tid >> 6, lane = tid & 63;
  const int fr = lane & 15, fg = lane >> 4;
  const int m0 = blockIdx.x * 128, n0 = blockIdx.y * 128;
  const int wr = wid >> 2, wc = wid & 3;       // 2x4 wave grid: 64x32 per wave
  const int srow = lane >> 3, scol = (lane & 7) << 3;  // chunk: 8 rows x 128B
  f32x4 acc[4][2] = {};

  for (int k0 = 0; k0 < K; k0 += 64) {
    __syncthreads();
#pragma unroll
    for (int i = 0; i < 2; ++i) {
      const int c = wid + i * 8;  // 16 chunks of 1KB per matrix
      gll16(&A[(size_t)(m0 + c * 8 + srow) * K + k0 + scol], &As[c * 8][0]);
      gll16(&B[(size_t)(n0 + c * 8 + srow) * K + k0 + scol], &Bs[c * 8][0]);
    }
    __syncthreads();
#pragma unroll
    for (int ks = 0; ks < 2; ++ks) {
      short8 a[4], b[2];
#pragma unroll
      for (int i = 0; i < 4; ++i)
        a[i] = *reinterpret_cast<const short8*>(
            &As[wr * 64 + i * 16 + fr][ks * 32 + fg * 8]);
#pragma unroll
      for (int j = 0; j < 2; ++j)
        b[j] = *reinterpret_cast<const short8*>(
            &Bs[wc * 32 + j * 16 + fr][ks * 32 + fg * 8]);
#pragma unroll
      for (int i = 0; i < 4; ++i)
#pragma unroll
        for (int j = 0; j < 2; ++j)
          acc[i][j] = __builtin_amdgcn_mfma_f32_16x16x32_bf16(a[i], b[j], acc[i][j], 0, 0, 0);
    }
  }

  const int rb = fg * 4;
#pragma unroll
  for (int i = 0; i < 4; ++i)
#pragma unroll
    for (int j = 0; j < 2; ++j) {
      const int row0 = m0 + wr * 64 + i * 16 + rb;
      const int col = n0 + wc * 32 + j * 16 + fr;
#pragma unroll
      for (int r = 0; r < 4; ++r) {
        size_t idx = (size_t)(row0 + r) * N + col;
        if (OUT_BF16) ((u16*)Cv)[idx] = f2b(acc[i][j][r]);
        else          ((float*)Cv)[idx] = acc[i][j][r];
      }
    }
}

// ---------------- per-head RMSNorm + RoPE (Q,K only) ----------------
// Q additionally scaled by 1/sqrt(HD) * log2(e) so attention runs in exp2 domain.
__global__ __launch_bounds__(256) void normrope(const u16* __restrict__ qkv,
                                                const int* __restrict__ pos_ids,
                                                const float* __restrict__ cosT,
                                                const float* __restrict__ sinT,
                                                const float* __restrict__ qw,
                                                const float* __restrict__ kw,
                                                u16* __restrict__ Qn,
                                                u16* __restrict__ Kn) {
  const int w = blockIdx.x * 4 + (threadIdx.x >> 6);
  const int lane = threadIdx.x & 63;
  const int row = w / 20, unit = w % 20;
  const int b = row >> 11, s = row & 2047;
  float x = b2f(qkv[(size_t)row * 1536 + unit * 64 + lane]);
  const bool isq = unit < 16;
  const int h = isq ? unit : unit - 16;
  float ss = x * x;
  ss += __shfl_xor(ss, 1);
  ss += __shfl_xor(ss, 2);
  ss += __shfl_xor(ss, 4);
  ss += __shfl_xor(ss, 8);
  ss += __shfl_xor(ss, 16);
  ss += __shfl_xor(ss, 32);
  float r = rsqrtf(ss * (1.0f / 64.0f) + 1e-6f);
  float xn = x * r * (isq ? qw[lane] * 0.18033688011112042f : kw[lane]);
  const int p = pos_ids[row];
  const float c = cosT[p * 64 + lane];
  const float sn = sinT[p * 64 + lane];
  float partner = __shfl_xor(xn, 32);
  float out = xn * c + (lane < 32 ? -partner : partner) * sn;
  if (isq) Qn[((size_t)(b * NH + h) * S_LEN + s) * HD + lane] = f2b(out);
  else     Kn[((size_t)(b * NKV + h) * S_LEN + s) * HD + lane] = f2b(out);
}

// ---------------- V transpose via LDS tiles, sigma-permuted columns ---------
// Vp[d][32-block base + i] = V[d][base + sigma(i)],
// sigma(i) = 8*(2*mf + (mm>>2)) + 4*hi + (mm&3), i = 16mf + 8hi + mm.
// This makes PV's B-fragment = packed p's directly (no cross-lane exchange).
__global__ __launch_bounds__(256) void vtrans(const u16* __restrict__ qkv,
                                              u16* __restrict__ Vt) {
  const int s0 = blockIdx.x * 64;
  const int b = blockIdx.y >> 2, hv = blockIdx.y & 3;
  __shared__ u16 t[64][72];
  const int tid = threadIdx.x;
  const int r = tid >> 2, cq = (tid & 3) << 4;
#pragma unroll
  for (int i = 0; i < 2; ++i)
    *reinterpret_cast<short8*>(&t[r][cq + i * 8]) =
        *reinterpret_cast<const short8*>(
            &qkv[(size_t)(b * S_LEN + s0 + r) * 1536 + 1280 + hv * 64 + cq + i * 8]);
  __syncthreads();
  const int d = tid >> 2, sq = (tid & 3) << 4;
#pragma unroll
  for (int i = 0; i < 2; ++i) {
    u16 tmp[8];
#pragma unroll
    for (int k = 0; k < 8; ++k) {
      const int sl = sq + i * 8 + k;
      const int sp = (sl & 32) + 8 * (2 * ((sl >> 4) & 1) + ((sl >> 2) & 1)) +
                     4 * ((sl >> 3) & 1) + (sl & 3);
      tmp[k] = t[sp][d];
    }
    *reinterpret_cast<short8*>(
        &Vt[((size_t)(b * NKV + hv) * HD + d) * S_LEN + s0 + sq + i * 8]) =
        *reinterpret_cast<short8*>(tmp);
  }
}

// ---------------- attention tile: swapped QK^T, exp2 softmax, in-lane P -----
__device__ __forceinline__ void attn_tile(const u16* __restrict__ K,
                                          const u16* __restrict__ V,
                                          const short8 qf[4], int kv0, bool domask,
                                          int col, int hi,
                                          f32x16& o0, f32x16& o1, float& m, float& l) {
  // V loads issued early (in flight under QK + softmax)
  short8 v0 = *reinterpret_cast<const short8*>(&V[(size_t)col * S_LEN + kv0 + hi * 8]);
  short8 v1 = *reinterpret_cast<const short8*>(&V[(size_t)col * S_LEN + kv0 + 16 + hi * 8]);
  short8 v2 = *reinterpret_cast<const short8*>(&V[(size_t)(32 + col) * S_LEN + kv0 + hi * 8]);
  short8 v3 = *reinterpret_cast<const short8*>(&V[(size_t)(32 + col) * S_LEN + kv0 + 16 + hi * 8]);
  // QK: two independent accumulator chains, summed once
  f32x16 sA = {}, sB = {};
  {
    short8 k0 = *reinterpret_cast<const short8*>(&K[(size_t)(kv0 + col) * HD + hi * 8]);
    short8 k1 = *reinterpret_cast<const short8*>(&K[(size_t)(kv0 + col) * HD + 16 + hi * 8]);
    short8 k2 = *reinterpret_cast<const short8*>(&K[(size_t)(kv0 + col) * HD + 32 + hi * 8]);
    short8 k3 = *reinterpret_cast<const short8*>(&K[(size_t)(kv0 + col) * HD + 48 + hi * 8]);
    sA = __builtin_amdgcn_mfma_f32_32x32x16_bf16(k0, qf[0], sA, 0, 0, 0);
    sB = __builtin_amdgcn_mfma_f32_32x32x16_bf16(k1, qf[1], sB, 0, 0, 0);
    sA = __builtin_amdgcn_mfma_f32_32x32x16_bf16(k2, qf[2], sA, 0, 0, 0);
    sB = __builtin_amdgcn_mfma_f32_32x32x16_bf16(k3, qf[3], sB, 0, 0, 0);
  }
  f32x16 s = sA + sB;
  if (domask) {  // diagonal: mask kv > q (kv rel = (r&3)+8*(r>>2)+4*hi)
#pragma unroll
    for (int r = 0; r < 16; ++r) {
      int kvr = (r & 3) + 8 * (r >> 2) + 4 * hi;
      s[r] = (kvr <= col) ? s[r] : -3.0e38f;
    }
  }
  float t8[8];
#pragma unroll
  for (int r = 0; r < 8; ++r) t8[r] = fmaxf(s[r], s[r + 8]);
#pragma unroll
  for (int r = 0; r < 4; ++r) t8[r] = fmaxf(t8[r], t8[r + 4]);
  float tm = fmaxf(fmaxf(t8[0], t8[1]), fmaxf(t8[2], t8[3]));
  tm = fmaxf(tm, __shfl_xor(tm, 32));
  // defer-max: skip rescale unless max grew past 2^8 headroom
  if (!__all(tm <= m + 8.0f)) {
    float mn = fmaxf(m, tm);
    float al = exp2f(m - mn);
    m = mn;
    l *= al;
#pragma unroll
    for (int r = 0; r < 16; ++r) { o0[r] *= al; o1[r] *= al; }
  }
  float p[16];
#pragma unroll
  for (int r = 0; r < 16; ++r) p[r] = exp2f(s[r] - m);
  float u8[8];
#pragma unroll
  for (int r = 0; r < 8; ++r) u8[r] = p[r] + p[r + 8];
#pragma unroll
  for (int r = 0; r < 4; ++r) u8[r] += u8[r + 4];
  float ps = (u8[0] + u8[1]) + (u8[2] + u8[3]);
  ps += __shfl_xor(ps, 32);
  l += ps;
  // pack P -> bf16: with sigma-permuted V, B0 = p[0..7], B1 = p[8..15] in-lane
  uint32_t w[8];
#pragma unroll
  for (int i = 0; i < 8; ++i) {
    uint32_t wo;
    asm("v_cvt_pk_bf16_f32 %0, %1, %2" : "=v"(wo) : "v"(p[2 * i]), "v"(p[2 * i + 1]));
    w[i] = wo;
  }
  u32x4 bw0 = {w[0], w[1], w[2], w[3]};
  u32x4 bw1 = {w[4], w[5], w[6], w[7]};
  short8 B0 = __builtin_bit_cast(short8, bw0);
  short8 B1 = __builtin_bit_cast(short8, bw1);
  o0 = __builtin_amdgcn_mfma_f32_32x32x16_bf16(v0, B0, o0, 0, 0, 0);
  o0 = __builtin_amdgcn_mfma_f32_32x32x16_bf16(v1, B1, o0, 0, 0, 0);
  o1 = __builtin_amdgcn_mfma_f32_32x32x16_bf16(v2, B0, o1, 0, 0, 0);
  o1 = __builtin_amdgcn_mfma_f32_32x32x16_bf16(v3, B1, o1, 0, 0, 0);
}

// ---------------- attention pass 1: independent (q-tile, kv-chunk) waves ----
// grid (64, B*NH), 4 waves. Wave ck handles kv tiles [16ck, min(16ck+15, qt)]
// for q-tile qt = 63-bx. No barriers, no inter-wave coupling. Writes partial
// (m, l, unnormalized O bf16) to workspace.
__global__ __launch_bounds__(256) void attn_pass1(const u16* __restrict__ Qn,
                                                  const u16* __restrict__ Kn,
                                                  const u16* __restrict__ Vt,
                                                  float* __restrict__ PML,
                                                  u16* __restrict__ PO) {
  const int bh = blockIdx.y;
  const int b = bh >> 4, h = bh & 15, hkv = h >> 2;
  const int wid = threadIdx.x >> 6, lane = threadIdx.x & 63;
  const int col = lane & 31, hi = lane >> 5;
  const int qt = 63 - blockIdx.x;  // heavy blocks dispatch first
  const int ck = wid;
  if (ck * 16 > qt) return;
  const int q0 = qt * 32;
  const u16* Q = Qn + (size_t)bh * S_LEN * HD;
  const u16* K = Kn + (size_t)(b * NKV + hkv) * S_LEN * HD;
  const u16* V = Vt + (size_t)(b * NKV + hkv) * HD * S_LEN;
  const int slot = (bh * 64 + qt) * 4 + ck;

  short8 qf[4];
#pragma unroll
  for (int d = 0; d < 4; ++d)
    qf[d] = *reinterpret_cast<const short8*>(&Q[(size_t)(q0 + col) * HD + d * 16 + hi * 8]);

  f32x16 o0 = {}, o1 = {};
  float m = -3.0e38f, l = 0.0f;
  const int kend = min(ck * 16 + 15, qt);
  for (int kt = ck * 16; kt <= kend; ++kt)
    attn_tile(K, V, qf, kt * 32, kt == qt, col, hi, o0, o1, m, l);

  // epilogue: wave-private LDS transpose, store unnormalized bf16 partial
  __shared__ __align__(16) u16 Tl[4][32][72];
#pragma unroll
  for (int r = 0; r < 16; ++r) {
    int dl = (r & 3) + 8 * (r >> 2) + 4 * hi;
    Tl[wid][col][dl] = f2b(o0[r]);
    Tl[wid][col][32 + dl] = f2b(o1[r]);
  }
#pragma unroll
  for (int k2 = 0; k2 < 4; ++k2) {
    short8 vv = *reinterpret_cast<const short8*>(&Tl[wid][col][hi * 32 + k2 * 8]);
    *reinterpret_cast<short8*>(
        &PO[(size_t)slot * 2048 + col * 64 + hi * 32 + k2 * 8]) = vv;
  }
  if (hi == 0) {
    PML[slot * 64 + col] = m;
    PML[slot * 64 + 32 + col] = l;
  }
}

// ---------------- attention pass 2: merge chunk partials -> ctx -------------
// grid (64, B*NH); thread t -> q = t>>3, d0 = (t&7)*8.
__global__ __launch_bounds__(256) void attn_merge(const float* __restrict__ PML,
                                                  const u16* __restrict__ PO,
                                                  u16* __restrict__ ctx) {
  const int qt = blockIdx.x, bh = blockIdx.y;
  const int b = bh >> 4, h = bh & 15;
  const int t = threadIdx.x;
  const int q = t >> 3, d0 = (t & 7) * 8;
  const int nck = (qt >> 4) + 1;
  const int base = (bh * 64 + qt) * 4;

  float M = -3.0e38f;
#pragma unroll 4
  for (int ck = 0; ck < nck; ++ck)
    M = fmaxf(M, PML[(base + ck) * 64 + q]);
  float L = 0.0f;
  float acc[8] = {};
#pragma unroll 4
  for (int ck = 0; ck < nck; ++ck) {
    float mm = PML[(base + ck) * 64 + q];
    float ll = PML[(base + ck) * 64 + 32 + q];
    float w = exp2f(mm - M);
    L += w * ll;
    short8 ov = *reinterpret_cast<const short8*>(
        &PO[(size_t)(base + ck) * 2048 + q * 64 + d0]);
#pragma unroll
    for (int k = 0; k < 8; ++k) acc[k] += w * b2f((u16)ov[k]);
  }
  const float invL = 1.0f / L;
  short8 outv;
#pragma unroll
  for (int k = 0; k < 8; ++k) outv[k] = (short)f2b(acc[k] * invL);
  *reinterpret_cast<short8*>(
      &ctx[((size_t)(b * S_LEN) + qt * 32 + q) * (NH * HD) + h * HD + d0]) = outv;
}

extern "C" void kernel_launch(void* const* d_in, const int* in_sizes, int n_in,
                              void* d_out, int out_size, void* d_ws, size_t ws_size,
                              hipStream_t stream) {
  const float* hidden = (const float*)d_in[0];
  const float* cosT   = (const float*)d_in[1];
  const float* sinT   = (const float*)d_in[2];
  const int*   pos    = (const int*)d_in[3];
  // d_in[4] attention_mask: causal tril, applied analytically in attention
  const float* Wq = (const float*)d_in[5];
  const float* Wk = (const float*)d_in[6];
  const float* Wv = (const float*)d_in[7];
  const float* Wo = (const float*)d_in[8];
  const float* qw = (const float*)d_in[9];
  const float* kw = (const float*)d_in[10];

  char* p = (char*)d_ws;
  u16* hb   = (u16*)p; p += (size_t)4096 * 1024 * 2;
  u16* wqkv = (u16*)p; p += (size_t)1536 * 1024 * 2;
  u16* wob  = (u16*)p; p += (size_t)1024 * 1024 * 2;
  u16* qkvr = (u16*)p; p += (size_t)4096 * 1536 * 2;
  u16* qn   = (u16*)p; p += (size_t)(NH * 2) * S_LEN * HD * 2;
  u16* kn   = (u16*)p; p += (size_t)(NKV * 2) * S_LEN * HD * 2;
  u16* vt   = (u16*)p; p += (size_t)(NKV * 2) * HD * S_LEN * 2;
  u16* ctx  = (u16*)p; p += (size_t)4096 * 1024 * 2;
  float* pml = (float*)p; p += (size_t)8192 * 64 * 4;   // 2 MB partial m,l
  u16* po   = (u16*)p; p += (size_t)8192 * 2048 * 2;    // 32 MB partial O

  f2b_multi<<<3332, 256, 0, stream>>>(hidden, hb, 524288,
                                      Wq, wqkv, 131072,
                                      Wk, wqkv + 1048576, 32768,
                                      Wv, wqkv + 1310720, 32768,
                                      Wo, wob, 131072);

  gemm_bt<1><<<dim3(32, 12), 512, 0, stream>>>(hb, wqkv, qkvr, 4096, 1536, 1024);

  normrope<<<20480, 256, 0, stream>>>(qkvr, pos, cosT, sinT, qw, kw, qn, kn);
  vtrans<<<dim3(32, 8), 256, 0, stream>>>(qkvr, vt);

  // attention: two-pass flash-decoding, fully independent waves in pass 1
  attn_pass1<<<dim3(64, 2 * NH), 256, 0, stream>>>(qn, kn, vt, pml, po);
  attn_merge<<<dim3(64, 2 * NH), 256, 0, stream>>>(pml, po, ctx);

  gemm_bt<0><<<dim3(32, 8), 512, 0, stream>>>(ctx, wob, d_out, 4096, 1024, 1024);
}

// Round 13
// 245.691 us; speedup vs baseline: 1.1468x; 1.1468x over previous
//
#include <hip/hip_runtime.h>
#include <stdint.h>

#define S_LEN 2048
#define HIDDEN 1024
#define NH 16
#define NKV 4
#define HD 64

typedef unsigned short u16;
typedef __attribute__((ext_vector_type(8))) short short8;
typedef __attribute__((ext_vector_type(4))) float f32x4;
typedef __attribute__((ext_vector_type(16))) float f32x16;
typedef __attribute__((ext_vector_type(4))) uint32_t u32x4;

__device__ __forceinline__ u16 f2b(float f) {
  uint32_t u = __float_as_uint(f);
  uint32_t r = u + 0x7fffu + ((u >> 16) & 1u);
  return (u16)(r >> 16);
}
__device__ __forceinline__ float b2f(u16 b) {
  return __uint_as_float(((uint32_t)b) << 16);
}
__device__ __forceinline__ void gll16(const void* g, void* l) {
  __builtin_amdgcn_global_load_lds(
      (const __attribute__((address_space(1))) uint32_t*)g,
      (__attribute__((address_space(3))) uint32_t*)l, 16, 0, 0);
}

// ---------------- fp32 -> bf16 convert, 5 buffers fused, 8 elem/thread ------
__global__ __launch_bounds__(256) void f2b_multi(
    const float* __restrict__ s0, u16* __restrict__ d0, int n0,
    const float* __restrict__ s1, u16* __restrict__ d1, int n1,
    const float* __restrict__ s2, u16* __restrict__ d2, int n2,
    const float* __restrict__ s3, u16* __restrict__ d3, int n3,
    const float* __restrict__ s4, u16* __restrict__ d4, int n4) {
  int i = blockIdx.x * 256 + threadIdx.x;
  const float* s;
  u16* d;
  int idx = i;
  if (i < n0) { s = s0; d = d0; }
  else if ((idx = i - n0) < n1) { s = s1; d = d1; }
  else if ((idx = i - n0 - n1) < n2) { s = s2; d = d2; }
  else if ((idx = i - n0 - n1 - n2) < n3) { s = s3; d = d3; }
  else if ((idx = i - n0 - n1 - n2 - n3) < n4) { s = s4; d = d4; }
  else return;
  f32x4 a = *reinterpret_cast<const f32x4*>(&s[(size_t)idx * 8]);
  f32x4 b = *reinterpret_cast<const f32x4*>(&s[(size_t)idx * 8 + 4]);
  short8 t;
#pragma unroll
  for (int k = 0; k < 4; ++k) t[k] = (short)f2b(a[k]);
#pragma unroll
  for (int k = 0; k < 4; ++k) t[4 + k] = (short)f2b(b[k]);
  *reinterpret_cast<short8*>(&d[(size_t)idx * 8]) = t;
}

// ---------------- bf16 GEMM: C = A * B^T (A:[M][K], B:[N][K]) ----------------
// 128x128 tile, BK=64, 8 waves (2M x 4N, each wave 64x32), mfma 16x16x32.
template <int OUT_BF16>
__global__ __launch_bounds__(512) void gemm_bt(const u16* __restrict__ A,
                                               const u16* __restrict__ B,
                                               void* __restrict__ Cv,
                                               int M, int N, int K) {
  __shared__ u16 As[128][64];
  __shared__ u16 Bs[128][64];
  const int tid = threadIdx.x;
  const int wid = tid >> 6, lane = tid & 63;
  const int fr = lane & 15, fg = lane >> 4;
  const int m0 = blockIdx.x * 128, n0 = blockIdx.y * 128;
  const int wr = wid >> 2, wc = wid & 3;       // 2x4 wave grid: 64x32 per wave
  const int srow = lane >> 3, scol = (lane & 7) << 3;  // chunk: 8 rows x 128B
  f32x4 acc[4][2] = {};

  for (int k0 = 0; k0 < K; k0 += 64) {
    __syncthreads();
#pragma unroll
    for (int i = 0; i < 2; ++i) {
      const int c = wid + i * 8;  // 16 chunks of 1KB per matrix
      gll16(&A[(size_t)(m0 + c * 8 + srow) * K + k0 + scol], &As[c * 8][0]);
      gll16(&B[(size_t)(n0 + c * 8 + srow) * K + k0 + scol], &Bs[c * 8][0]);
    }
    __syncthreads();
#pragma unroll
    for (int ks = 0; ks < 2; ++ks) {
      short8 a[4], b[2];
#pragma unroll
      for (int i = 0; i < 4; ++i)
        a[i] = *reinterpret_cast<const short8*>(
            &As[wr * 64 + i * 16 + fr][ks * 32 + fg * 8]);
#pragma unroll
      for (int j = 0; j < 2; ++j)
        b[j] = *reinterpret_cast<const short8*>(
            &Bs[wc * 32 + j * 16 + fr][ks * 32 + fg * 8]);
#pragma unroll
      for (int i = 0; i < 4; ++i)
#pragma unroll
        for (int j = 0; j < 2; ++j)
          acc[i][j] = __builtin_amdgcn_mfma_f32_16x16x32_bf16(a[i], b[j], acc[i][j], 0, 0, 0);
    }
  }

  const int rb = fg * 4;
#pragma unroll
  for (int i = 0; i < 4; ++i)
#pragma unroll
    for (int j = 0; j < 2; ++j) {
      const int row0 = m0 + wr * 64 + i * 16 + rb;
      const int col = n0 + wc * 32 + j * 16 + fr;
#pragma unroll
      for (int r = 0; r < 4; ++r) {
        size_t idx = (size_t)(row0 + r) * N + col;
        if (OUT_BF16) ((u16*)Cv)[idx] = f2b(acc[i][j][r]);
        else          ((float*)Cv)[idx] = acc[i][j][r];
      }
    }
}

// ---------------- per-head RMSNorm + RoPE (Q,K only) ----------------
// Q additionally scaled by 1/sqrt(HD) * log2(e) so attention runs in exp2 domain.
__global__ __launch_bounds__(256) void normrope(const u16* __restrict__ qkv,
                                                const int* __restrict__ pos_ids,
                                                const float* __restrict__ cosT,
                                                const float* __restrict__ sinT,
                                                const float* __restrict__ qw,
                                                const float* __restrict__ kw,
                                                u16* __restrict__ Qn,
                                                u16* __restrict__ Kn) {
  const int w = blockIdx.x * 4 + (threadIdx.x >> 6);
  const int lane = threadIdx.x & 63;
  const int row = w / 20, unit = w % 20;
  const int b = row >> 11, s = row & 2047;
  float x = b2f(qkv[(size_t)row * 1536 + unit * 64 + lane]);
  const bool isq = unit < 16;
  const int h = isq ? unit : unit - 16;
  float ss = x * x;
  ss += __shfl_xor(ss, 1);
  ss += __shfl_xor(ss, 2);
  ss += __shfl_xor(ss, 4);
  ss += __shfl_xor(ss, 8);
  ss += __shfl_xor(ss, 16);
  ss += __shfl_xor(ss, 32);
  float r = rsqrtf(ss * (1.0f / 64.0f) + 1e-6f);
  float xn = x * r * (isq ? qw[lane] * 0.18033688011112042f : kw[lane]);
  const int p = pos_ids[row];
  const float c = cosT[p * 64 + lane];
  const float sn = sinT[p * 64 + lane];
  float partner = __shfl_xor(xn, 32);
  float out = xn * c + (lane < 32 ? -partner : partner) * sn;
  if (isq) Qn[((size_t)(b * NH + h) * S_LEN + s) * HD + lane] = f2b(out);
  else     Kn[((size_t)(b * NKV + h) * S_LEN + s) * HD + lane] = f2b(out);
}

// ---------------- V transpose via LDS tiles, sigma-permuted columns ---------
// Vp[d][32-block base + i] = V[d][base + sigma(i)],
// sigma(i) = 8*(2*mf + (mm>>2)) + 4*hi + (mm&3), i = 16mf + 8hi + mm.
// Makes PV's B-fragment = packed p's directly (no cross-lane exchange).
// Verified end-to-end in R10 (passed, absmax 0.0078).
__global__ __launch_bounds__(256) void vtrans(const u16* __restrict__ qkv,
                                              u16* __restrict__ Vt) {
  const int s0 = blockIdx.x * 64;
  const int b = blockIdx.y >> 2, hv = blockIdx.y & 3;
  __shared__ u16 t[64][72];
  const int tid = threadIdx.x;
  const int r = tid >> 2, cq = (tid & 3) << 4;
#pragma unroll
  for (int i = 0; i < 2; ++i)
    *reinterpret_cast<short8*>(&t[r][cq + i * 8]) =
        *reinterpret_cast<const short8*>(
            &qkv[(size_t)(b * S_LEN + s0 + r) * 1536 + 1280 + hv * 64 + cq + i * 8]);
  __syncthreads();
  const int d = tid >> 2, sq = (tid & 3) << 4;
#pragma unroll
  for (int i = 0; i < 2; ++i) {
    u16 tmp[8];
#pragma unroll
    for (int k = 0; k < 8; ++k) {
      const int sl = sq + i * 8 + k;
      const int sp = (sl & 32) + 8 * (2 * ((sl >> 4) & 1) + ((sl >> 2) & 1)) +
                     4 * ((sl >> 3) & 1) + (sl & 3);
      tmp[k] = t[sp][d];
    }
    *reinterpret_cast<short8*>(
        &Vt[((size_t)(b * NKV + hv) * HD + d) * S_LEN + s0 + sq + i * 8]) =
        *reinterpret_cast<short8*>(tmp);
  }
}

// ---------------- attention tile: swapped QK^T, exp2 softmax, in-lane P -----
// Cross-lane: only the 2 reduce shfl_xor(32) ops remain (verified form).
__device__ __forceinline__ void attn_tile(const u16* __restrict__ K,
                                          const u16* __restrict__ V,
                                          const short8 qf[4], int kv0, bool domask,
                                          int col, int hi,
                                          f32x16& o0, f32x16& o1, float& m, float& l) {
  // V loads issued early (in flight under QK + softmax)
  short8 v0 = *reinterpret_cast<const short8*>(&V[(size_t)col * S_LEN + kv0 + hi * 8]);
  short8 v1 = *reinterpret_cast<const short8*>(&V[(size_t)col * S_LEN + kv0 + 16 + hi * 8]);
  short8 v2 = *reinterpret_cast<const short8*>(&V[(size_t)(32 + col) * S_LEN + kv0 + hi * 8]);
  short8 v3 = *reinterpret_cast<const short8*>(&V[(size_t)(32 + col) * S_LEN + kv0 + 16 + hi * 8]);
  // QK: two independent accumulator chains, summed once
  f32x16 sA = {}, sB = {};
  {
    short8 k0 = *reinterpret_cast<const short8*>(&K[(size_t)(kv0 + col) * HD + hi * 8]);
    short8 k1 = *reinterpret_cast<const short8*>(&K[(size_t)(kv0 + col) * HD + 16 + hi * 8]);
    short8 k2 = *reinterpret_cast<const short8*>(&K[(size_t)(kv0 + col) * HD + 32 + hi * 8]);
    short8 k3 = *reinterpret_cast<const short8*>(&K[(size_t)(kv0 + col) * HD + 48 + hi * 8]);
    sA = __builtin_amdgcn_mfma_f32_32x32x16_bf16(k0, qf[0], sA, 0, 0, 0);
    sB = __builtin_amdgcn_mfma_f32_32x32x16_bf16(k1, qf[1], sB, 0, 0, 0);
    sA = __builtin_amdgcn_mfma_f32_32x32x16_bf16(k2, qf[2], sA, 0, 0, 0);
    sB = __builtin_amdgcn_mfma_f32_32x32x16_bf16(k3, qf[3], sB, 0, 0, 0);
  }
  f32x16 s = sA + sB;
  if (domask) {  // diagonal: mask kv > q (kv rel = (r&3)+8*(r>>2)+4*hi)
#pragma unroll
    for (int r = 0; r < 16; ++r) {
      int kvr = (r & 3) + 8 * (r >> 2) + 4 * hi;
      s[r] = (kvr <= col) ? s[r] : -3.0e38f;
    }
  }
  float t8[8];
#pragma unroll
  for (int r = 0; r < 8; ++r) t8[r] = fmaxf(s[r], s[r + 8]);
#pragma unroll
  for (int r = 0; r < 4; ++r) t8[r] = fmaxf(t8[r], t8[r + 4]);
  float tm = fmaxf(fmaxf(t8[0], t8[1]), fmaxf(t8[2], t8[3]));
  tm = fmaxf(tm, __shfl_xor(tm, 32));
  // defer-max: skip rescale unless max grew past 2^8 headroom
  if (!__all(tm <= m + 8.0f)) {
    float mn = fmaxf(m, tm);
    float al = exp2f(m - mn);
    m = mn;
    l *= al;
#pragma unroll
    for (int r = 0; r < 16; ++r) { o0[r] *= al; o1[r] *= al; }
  }
  float p[16];
#pragma unroll
  for (int r = 0; r < 16; ++r) p[r] = exp2f(s[r] - m);
  float u8[8];
#pragma unroll
  for (int r = 0; r < 8; ++r) u8[r] = p[r] + p[r + 8];
#pragma unroll
  for (int r = 0; r < 4; ++r) u8[r] += u8[r + 4];
  float ps = (u8[0] + u8[1]) + (u8[2] + u8[3]);
  ps += __shfl_xor(ps, 32);
  l += ps;
  // pack P -> bf16: with sigma-permuted V, B0 = p[0..7], B1 = p[8..15] in-lane
  uint32_t w[8];
#pragma unroll
  for (int i = 0; i < 8; ++i) {
    uint32_t wo;
    asm("v_cvt_pk_bf16_f32 %0, %1, %2" : "=v"(wo) : "v"(p[2 * i]), "v"(p[2 * i + 1]));
    w[i] = wo;
  }
  u32x4 bw0 = {w[0], w[1], w[2], w[3]};
  u32x4 bw1 = {w[4], w[5], w[6], w[7]};
  short8 B0 = __builtin_bit_cast(short8, bw0);
  short8 B1 = __builtin_bit_cast(short8, bw1);
  o0 = __builtin_amdgcn_mfma_f32_32x32x16_bf16(v0, B0, o0, 0, 0, 0);
  o0 = __builtin_amdgcn_mfma_f32_32x32x16_bf16(v1, B1, o0, 0, 0, 0);
  o1 = __builtin_amdgcn_mfma_f32_32x32x16_bf16(v2, B0, o1, 0, 0, 0);
  o1 = __builtin_amdgcn_mfma_f32_32x32x16_bf16(v3, B1, o1, 0, 0, 0);
}

// ---------------- flash attention: per-wave q-tile, dual-state ILP-2 --------
// R8 structure (known 84us): grid (16, B*NH), 4 waves, equal-work q-tiles,
// no barriers, no inter-wave coupling.
__global__ __launch_bounds__(256) void attn_kernel(const u16* __restrict__ Qn,
                                                   const u16* __restrict__ Kn,
                                                   const u16* __restrict__ Vt,
                                                   u16* __restrict__ ctx) {
  const int bh = blockIdx.y;
  const int b = bh >> 4, h = bh & 15, hkv = h >> 2;
  const u16* Q = Qn + (size_t)bh * S_LEN * HD;
  const u16* K = Kn + (size_t)(b * NKV + hkv) * S_LEN * HD;
  const u16* V = Vt + (size_t)(b * NKV + hkv) * HD * S_LEN;
  const int wid = threadIdx.x >> 6, lane = threadIdx.x & 63;
  const int col = lane & 31, hi = lane >> 5;
  const int j = blockIdx.x;
  int qt;
  if (wid == 0) qt = j;
  else if (wid == 1) qt = 31 - j;
  else if (wid == 2) qt = 32 + j;
  else qt = 63 - j;
  const int q0 = qt * 32;

  short8 qf[4];
#pragma unroll
  for (int d = 0; d < 4; ++d)
    qf[d] = *reinterpret_cast<const short8*>(&Q[(size_t)(q0 + col) * HD + d * 16 + hi * 8]);

  f32x16 oA0 = {}, oA1 = {}, oB0 = {}, oB1 = {};
  float mA = -3.0e38f, lA = 0.0f, mB = -3.0e38f, lB = 0.0f;

  int kt = 0;
  for (; kt + 1 <= qt; kt += 2) {
    attn_tile(K, V, qf, kt * 32, false, col, hi, oA0, oA1, mA, lA);
    attn_tile(K, V, qf, (kt + 1) * 32, kt + 1 == qt, col, hi, oB0, oB1, mB, lB);
  }
  if (kt <= qt)
    attn_tile(K, V, qf, kt * 32, kt == qt, col, hi, oA0, oA1, mA, lA);

  // merge states A,B in-register
  float M = fmaxf(mA, mB);
  float wA = exp2f(mA - M), wB = exp2f(mB - M);
  float l = wA * lA + wB * lB;
  const float invl = 1.0f / l;
  __shared__ __align__(16) u16 Tl[4][32][72];
#pragma unroll
  for (int r = 0; r < 16; ++r) {
    int dl = (r & 3) + 8 * (r >> 2) + 4 * hi;
    Tl[wid][col][dl] = f2b((wA * oA0[r] + wB * oB0[r]) * invl);
    Tl[wid][col][32 + dl] = f2b((wA * oA1[r] + wB * oB1[r]) * invl);
  }
#pragma unroll
  for (int k2 = 0; k2 < 4; ++k2) {
    short8 vv = *reinterpret_cast<const short8*>(&Tl[wid][col][hi * 32 + k2 * 8]);
    *reinterpret_cast<short8*>(
        &ctx[((size_t)(b * S_LEN) + q0 + col) * (NH * HD) + h * HD + hi * 32 + k2 * 8]) = vv;
  }
}

extern "C" void kernel_launch(void* const* d_in, const int* in_sizes, int n_in,
                              void* d_out, int out_size, void* d_ws, size_t ws_size,
                              hipStream_t stream) {
  const float* hidden = (const float*)d_in[0];
  const float* cosT   = (const float*)d_in[1];
  const float* sinT   = (const float*)d_in[2];
  const int*   pos    = (const int*)d_in[3];
  // d_in[4] attention_mask: causal tril, applied analytically in attn_kernel
  const float* Wq = (const float*)d_in[5];
  const float* Wk = (const float*)d_in[6];
  const float* Wv = (const float*)d_in[7];
  const float* Wo = (const float*)d_in[8];
  const float* qw = (const float*)d_in[9];
  const float* kw = (const float*)d_in[10];

  char* p = (char*)d_ws;
  u16* hb   = (u16*)p; p += (size_t)4096 * 1024 * 2;
  u16* wqkv = (u16*)p; p += (size_t)1536 * 1024 * 2;
  u16* wob  = (u16*)p; p += (size_t)1024 * 1024 * 2;
  u16* qkvr = (u16*)p; p += (size_t)4096 * 1536 * 2;
  u16* qn   = (u16*)p; p += (size_t)(NH * 2) * S_LEN * HD * 2;
  u16* kn   = (u16*)p; p += (size_t)(NKV * 2) * S_LEN * HD * 2;
  u16* vt   = (u16*)p; p += (size_t)(NKV * 2) * HD * S_LEN * 2;
  u16* ctx  = (u16*)p; p += (size_t)4096 * 1024 * 2;

  f2b_multi<<<3332, 256, 0, stream>>>(hidden, hb, 524288,
                                      Wq, wqkv, 131072,
                                      Wk, wqkv + 1048576, 32768,
                                      Wv, wqkv + 1310720, 32768,
                                      Wo, wob, 131072);

  gemm_bt<1><<<dim3(32, 12), 512, 0, stream>>>(hb, wqkv, qkvr, 4096, 1536, 1024);

  normrope<<<20480, 256, 0, stream>>>(qkvr, pos, cosT, sinT, qw, kw, qn, kn);
  vtrans<<<dim3(32, 8), 256, 0, stream>>>(qkvr, vt);

  // attention: 16 blocks x (B*NH); each block = 4 equal-work q-tiles
  attn_kernel<<<dim3(16, 2 * NH), 256, 0, stream>>>(qn, kn, vt, ctx);

  gemm_bt<0><<<dim3(32, 8), 512, 0, stream>>>(ctx, wob, d_out, 4096, 1024, 1024);
}